// Round 1
// baseline (2725.799 us; speedup 1.0000x reference)
//
#include <hip/hip_runtime.h>

#define B_ 512
#define T_ 48
#define D_ 128
#define F_ 16
#define H_ 512
// K = D_*F_ = 2048, gates = 4*H_ = 2048, M = T_*B_ = 24576

typedef float f32x4 __attribute__((ext_vector_type(4)));
typedef short s16x8 __attribute__((ext_vector_type(8)));
typedef unsigned short u16x8 __attribute__((ext_vector_type(8)));
typedef unsigned short u16x4 __attribute__((ext_vector_type(4)));

__device__ __forceinline__ unsigned short f2bf(float x) {
  unsigned u = __float_as_uint(x);
  u += 0x7fffu + ((u >> 16) & 1u);   // round-to-nearest-even
  return (unsigned short)(u >> 16);
}
__device__ __forceinline__ float bf2f(unsigned short h) {
  return __uint_as_float(((unsigned)h) << 16);
}

#define AS1 __attribute__((address_space(1)))
#define AS3 __attribute__((address_space(3)))
__device__ __forceinline__ void g2lds16(const void* g, void* l) {
  // async global->LDS, 16B per lane; LDS dest = wave-uniform base + lane*16
  __builtin_amdgcn_global_load_lds((const AS1 void*)g, (AS3 void*)l, 16, 0, 0);
}

// ---------------- K_prep: fp32 -> bf16 weight conversion ----------------
__global__ __launch_bounds__(256) void k_prep(const float* __restrict__ wih,
                                              const float* __restrict__ whh,
                                              unsigned short* __restrict__ wih_b,
                                              unsigned short* __restrict__ whh_b) {
  long i4 = ((long)blockIdx.x * 256 + threadIdx.x) * 4;
  if (i4 < 4194304) {
    float4 v = *(const float4*)(wih + i4);
    u16x4 o = {f2bf(v.x), f2bf(v.y), f2bf(v.z), f2bf(v.w)};
    *(u16x4*)(wih_b + i4) = o;
  } else {
    long j = i4 - 4194304;
    if (j < 1048576) {
      float4 v = *(const float4*)(whh + j);
      u16x4 o = {f2bf(v.x), f2bf(v.y), f2bf(v.z), f2bf(v.w)};
      *(u16x4*)(whh_b + j) = o;
    }
  }
}

// ---------------- K_ex: e_x = x_flat @ w_x + b, then softmax over D -----
__global__ __launch_bounds__(128) void k_ex(const float* __restrict__ in,
                                            const float* __restrict__ attn_w,
                                            const float* __restrict__ attn_b,
                                            float* __restrict__ a_out) {
  __shared__ float wx[768];
  __shared__ float red[128];
  const int b = blockIdx.x, d = threadIdx.x;
  for (int i = d; i < 768; i += 128) wx[i] = attn_w[1024 + i];
  __syncthreads();
  const float* base = in + (long)b * 98304 + (long)d * 16;
  float acc = 0.f;
  for (int t = 0; t < 48; ++t) {
    const float4* p = (const float4*)(base + (long)t * 2048);
    float4 v0 = p[0], v1 = p[1], v2 = p[2], v3 = p[3];
    acc += v0.x * wx[t]       + v0.y * wx[48 + t]  + v0.z * wx[96 + t]  + v0.w * wx[144 + t];
    acc += v1.x * wx[192 + t] + v1.y * wx[240 + t] + v1.z * wx[288 + t] + v1.w * wx[336 + t];
    acc += v2.x * wx[384 + t] + v2.y * wx[432 + t] + v2.z * wx[480 + t] + v2.w * wx[528 + t];
    acc += v3.x * wx[576 + t] + v3.y * wx[624 + t] + v3.z * wx[672 + t] + v3.w * wx[720 + t];
  }
  acc += attn_b[0];
  red[d] = acc;
  __syncthreads();
  for (int s = 64; s > 0; s >>= 1) {
    if (d < s) red[d] = fmaxf(red[d], red[d + s]);
    __syncthreads();
  }
  float mx = red[0];
  __syncthreads();
  float ex = expf(acc - mx);
  red[d] = ex;
  __syncthreads();
  for (int s = 64; s > 0; s >>= 1) {
    if (d < s) red[d] += red[d + s];
    __syncthreads();
  }
  a_out[b * 128 + d] = ex / red[0];
}

// ---------------- K_xhat: x_hat[t*512+b][d*16+f] = a[b,d]*x[b,t,d,f] (bf16)
__global__ __launch_bounds__(256) void k_xhat(const float* __restrict__ in,
                                              const float* __restrict__ a,
                                              unsigned short* __restrict__ xh) {
  const int mrow = blockIdx.x;            // t*512 + b
  const int t = mrow >> 9, b = mrow & 511;
  const int tid = threadIdx.x;
  const int k = tid * 8;
  const int d = k >> 4;
  const int f0 = k & 15;
  const float* src = in + (((long)(b * 48 + t) * 128 + d) * 16 + f0);
  float4 v0 = *(const float4*)src;
  float4 v1 = *(const float4*)(src + 4);
  float s = a[b * 128 + d];
  u16x8 o;
  o[0] = f2bf(v0.x * s); o[1] = f2bf(v0.y * s); o[2] = f2bf(v0.z * s); o[3] = f2bf(v0.w * s);
  o[4] = f2bf(v1.x * s); o[5] = f2bf(v1.y * s); o[6] = f2bf(v1.z * s); o[7] = f2bf(v1.w * s);
  *(u16x8*)(xh + (long)mrow * 2048 + k) = o;
}

// ---------------- K_gemm: gates_x = x_hat @ w_ih^T  (bf16 MFMA, 128x128 tiles)
__global__ __launch_bounds__(256) void k_gemm(const unsigned short* __restrict__ A,
                                              const unsigned short* __restrict__ Bw,
                                              unsigned short* __restrict__ C) {
  __shared__ unsigned short Asm[128 * 64];
  __shared__ unsigned short Bsm[128 * 64];
  const int tid = threadIdx.x;
  const int wave = tid >> 6, lane = tid & 63;
  const int q = lane >> 4, l16 = lane & 15;
  const long m0 = (long)blockIdx.y * 128;
  const long n0 = (long)blockIdx.x * 128;
  const int wm = wave & 1, wn = wave >> 1;
  f32x4 acc[4][4];
  f32x4 zz = {0.f, 0.f, 0.f, 0.f};
#pragma unroll
  for (int i = 0; i < 4; ++i)
#pragma unroll
    for (int j = 0; j < 4; ++j) acc[i][j] = zz;
  const int srow = wave * 32 + (lane >> 3);
  const int scol = (lane & 7) * 8;
  const unsigned short* Ag = A + (m0 + srow) * 2048 + scol;
  const unsigned short* Bg = Bw + (n0 + srow) * 2048 + scol;
  for (int kt = 0; kt < 32; ++kt) {
    __syncthreads();
#pragma unroll
    for (int i = 0; i < 4; ++i) {
      g2lds16(Ag + (long)kt * 64 + (long)i * 8 * 2048, Asm + (wave * 32 + i * 8) * 64);
      g2lds16(Bg + (long)kt * 64 + (long)i * 8 * 2048, Bsm + (wave * 32 + i * 8) * 64);
    }
    asm volatile("s_waitcnt vmcnt(0)" ::: "memory");
    __syncthreads();
#pragma unroll
    for (int ks = 0; ks < 64; ks += 32) {
      s16x8 af[4], bv[4];
#pragma unroll
      for (int mt = 0; mt < 4; ++mt)
        af[mt] = *(const s16x8*)&Asm[(wm * 64 + mt * 16 + l16) * 64 + ks + q * 8];
#pragma unroll
      for (int nt = 0; nt < 4; ++nt)
        bv[nt] = *(const s16x8*)&Bsm[(wn * 64 + nt * 16 + l16) * 64 + ks + q * 8];
#pragma unroll
      for (int mt = 0; mt < 4; ++mt)
#pragma unroll
        for (int nt = 0; nt < 4; ++nt)
          acc[mt][nt] = __builtin_amdgcn_mfma_f32_16x16x32_bf16(af[mt], bv[nt], acc[mt][nt], 0, 0, 0);
    }
  }
#pragma unroll
  for (int mt = 0; mt < 4; ++mt)
#pragma unroll
    for (int nt = 0; nt < 4; ++nt)
#pragma unroll
      for (int r = 0; r < 4; ++r) {
        long m = m0 + wm * 64 + mt * 16 + q * 4 + r;
        long n = n0 + wn * 64 + nt * 16 + l16;
        C[m * 2048 + n] = f2bf(acc[mt][nt][r]);
      }
}

// ---------------- K_rec: persistent LSTM scan, 256 blocks (bt 0..15 x g 0..15)
// block (bt,g): batch rows [bt*32, +32), h-cols [g*32, +32) => gate cols q*512+g*32+r
__global__ __launch_bounds__(256) void k_rec(const unsigned short* __restrict__ gx,
                                             const unsigned short* __restrict__ whh_b,
                                             const float* __restrict__ b_ih,
                                             const float* __restrict__ b_hh,
                                             unsigned short* __restrict__ h_buf,
                                             float* __restrict__ out,
                                             unsigned int* __restrict__ bar) {
  __shared__ float gsm[4][32][33];
  const int tid = threadIdx.x;
  const int wave = tid >> 6, lane = tid & 63;  // wave == gate group q (i,f,g,o)
  const int q = lane >> 4, l16 = lane & 15;
  const int bt = blockIdx.x >> 4, g = blockIdx.x & 15;
  const int b0 = bt * 32;
  const int pm = tid >> 3, pr = (tid & 7) * 4;
  float creg[4] = {0.f, 0.f, 0.f, 0.f};
  float bias_[2];
#pragma unroll
  for (int nt = 0; nt < 2; ++nt) {
    int j = wave * 512 + g * 32 + nt * 16 + l16;
    bias_[nt] = b_ih[j] + b_hh[j];
  }
  f32x4 zz = {0.f, 0.f, 0.f, 0.f};
  for (int t = 0; t < 48; ++t) {
    f32x4 acc[2][2];
    acc[0][0] = zz; acc[0][1] = zz; acc[1][0] = zz; acc[1][1] = zz;
    if (t > 0) {
#pragma unroll 4
      for (int ks = 0; ks < 512; ks += 32) {
        s16x8 af[2], bv[2];
#pragma unroll
        for (int mt = 0; mt < 2; ++mt)
          af[mt] = *(const s16x8*)&h_buf[(b0 + mt * 16 + l16) * 512 + ks + q * 8];
#pragma unroll
        for (int nt = 0; nt < 2; ++nt) {
          int j = wave * 512 + g * 32 + nt * 16 + l16;
          bv[nt] = *(const s16x8*)&whh_b[(long)j * 512 + ks + q * 8];
        }
#pragma unroll
        for (int mt = 0; mt < 2; ++mt)
#pragma unroll
          for (int nt = 0; nt < 2; ++nt)
            acc[mt][nt] = __builtin_amdgcn_mfma_f32_16x16x32_bf16(af[mt], bv[nt], acc[mt][nt], 0, 0, 0);
      }
    }
    // gates = mfma + gates_x + bias -> LDS (cross-wave exchange of i,f,g,o)
#pragma unroll
    for (int mt = 0; mt < 2; ++mt)
#pragma unroll
      for (int nt = 0; nt < 2; ++nt) {
        int j = wave * 512 + g * 32 + nt * 16 + l16;
        long row = (long)t * 512 + b0 + mt * 16 + q * 4;
#pragma unroll
        for (int r = 0; r < 4; ++r) {
          float val = acc[mt][nt][r] + bf2f(gx[(row + r) * 2048 + j]) + bias_[nt];
          gsm[wave][mt * 16 + q * 4 + r][nt * 16 + l16] = val;
        }
      }
    __syncthreads();
    // pointwise LSTM cell; thread owns (b0+pm, r=pr..pr+3), c in registers
#pragma unroll
    for (int rr = 0; rr < 4; ++rr) {
      int r = pr + rr;
      float gi = gsm[0][pm][r], gf = gsm[1][pm][r], gg = gsm[2][pm][r], go = gsm[3][pm][r];
      float is = 1.f / (1.f + expf(-gi));
      float fs = 1.f / (1.f + expf(-gf));
      float gt = tanhf(gg);
      float os = 1.f / (1.f + expf(-go));
      creg[rr] = fs * creg[rr] + is * gt;
      float hv = os * tanhf(creg[rr]);
      out[(long)(b0 + pm) * (T_ * H_) + (long)t * H_ + g * 32 + r] = hv;
      h_buf[(b0 + pm) * H_ + g * 32 + r] = f2bf(hv);
    }
    __syncthreads();
    if (t < 47) {
      // barrier among the 16 blocks sharing this batch tile (monotonic counter)
      if (tid == 0) {
        __threadfence();
        atomicAdd(&bar[bt * 16], 1u);
        unsigned tgt = 16u * (unsigned)(t + 1);
        while (__hip_atomic_load(&bar[bt * 16], __ATOMIC_ACQUIRE, __HIP_MEMORY_SCOPE_AGENT) < tgt) {
          __builtin_amdgcn_s_sleep(8);
        }
      }
      __syncthreads();
      __threadfence();  // invalidate L1 so h_buf reads are fresh
    }
  }
}

extern "C" void kernel_launch(void* const* d_in, const int* in_sizes, int n_in,
                              void* d_out, int out_size, void* d_ws, size_t ws_size,
                              hipStream_t stream) {
  const float* input  = (const float*)d_in[0];
  const float* attn_w = (const float*)d_in[1];
  const float* attn_b = (const float*)d_in[2];
  const float* w_ih   = (const float*)d_in[3];
  const float* w_hh   = (const float*)d_in[4];
  const float* b_ih   = (const float*)d_in[5];
  const float* b_hh   = (const float*)d_in[6];
  float* out = (float*)d_out;

  char* ws = (char*)d_ws;
  unsigned int* bar     = (unsigned int*)ws;                   // [0, 1024)
  float* a_ws           = (float*)(ws + 1024);                 // 512*128*4   = 262144
  unsigned short* h_buf = (unsigned short*)(ws + 263168);      // 512*512*2   = 524288
  unsigned short* whh_b = (unsigned short*)(ws + 787456);      // 2048*512*2  = 2097152
  unsigned short* wih_b = (unsigned short*)(ws + 2884608);     // 2048*2048*2 = 8388608
  unsigned short* x_hat = (unsigned short*)(ws + 11273216);    // 24576*2048*2 = 100663296
  unsigned short* gxws  = (unsigned short*)(ws + 111936512);   // 24576*2048*2 = 100663296

  hipMemsetAsync(d_ws, 0, 1024, stream);
  hipLaunchKernelGGL(k_prep, dim3(5120), dim3(256), 0, stream, w_ih, w_hh, wih_b, whh_b);
  hipLaunchKernelGGL(k_ex, dim3(512), dim3(128), 0, stream, input, attn_w, attn_b, a_ws);
  hipLaunchKernelGGL(k_xhat, dim3(24576), dim3(256), 0, stream, input, a_ws, x_hat);
  hipLaunchKernelGGL(k_gemm, dim3(16, 192), dim3(256), 0, stream, x_hat, wih_b, gxws);
  hipLaunchKernelGGL(k_rec, dim3(256), dim3(256), 0, stream, gxws, whh_b, b_ih, b_hh, h_buf, out, bar);
}

// Round 3
// 1284.320 us; speedup vs baseline: 2.1224x; 2.1224x over previous
//
#include <hip/hip_runtime.h>

#define B_ 512
#define T_ 48
#define D_ 128
#define F_ 16
#define H_ 512
// K = D_*F_ = 2048, gates = 4*H_ = 2048, M = T_*B_ = 24576

typedef float f32x4 __attribute__((ext_vector_type(4)));
typedef short s16x8 __attribute__((ext_vector_type(8)));
typedef unsigned short u16x8 __attribute__((ext_vector_type(8)));
typedef unsigned short u16x4 __attribute__((ext_vector_type(4)));

__device__ __forceinline__ unsigned short f2bf(float x) {
  unsigned u = __float_as_uint(x);
  u += 0x7fffu + ((u >> 16) & 1u);   // round-to-nearest-even
  return (unsigned short)(u >> 16);
}
__device__ __forceinline__ float bf2f(unsigned short h) {
  return __uint_as_float(((unsigned)h) << 16);
}
__device__ __forceinline__ float sigmoidf_(float x) {
  return 1.f / (1.f + expf(-x));
}

#define AS1 __attribute__((address_space(1)))
#define AS3 __attribute__((address_space(3)))
__device__ __forceinline__ void g2lds16(const void* g, void* l) {
  __builtin_amdgcn_global_load_lds((const AS1 void*)g, (AS3 void*)l, 16, 0, 0);
}

// ---------------- K_prep: fp32 -> bf16 weight conversion ----------------
__global__ __launch_bounds__(256) void k_prep(const float* __restrict__ wih,
                                              const float* __restrict__ whh,
                                              unsigned short* __restrict__ wih_b,
                                              unsigned short* __restrict__ whh_b) {
  long i4 = ((long)blockIdx.x * 256 + threadIdx.x) * 4;
  if (i4 < 4194304) {
    float4 v = *(const float4*)(wih + i4);
    u16x4 o = {f2bf(v.x), f2bf(v.y), f2bf(v.z), f2bf(v.w)};
    *(u16x4*)(wih_b + i4) = o;
  } else {
    long j = i4 - 4194304;
    if (j < 1048576) {
      float4 v = *(const float4*)(whh + j);
      u16x4 o = {f2bf(v.x), f2bf(v.y), f2bf(v.z), f2bf(v.w)};
      *(u16x4*)(whh_b + j) = o;
    }
  }
}

// ---------------- K_ex: e_x = x_flat @ w_x + b, then softmax over D -----
__global__ __launch_bounds__(128) void k_ex(const float* __restrict__ in,
                                            const float* __restrict__ attn_w,
                                            const float* __restrict__ attn_b,
                                            float* __restrict__ a_out) {
  __shared__ float wx[768];
  __shared__ float red[128];
  const int b = blockIdx.x, d = threadIdx.x;
  for (int i = d; i < 768; i += 128) wx[i] = attn_w[1024 + i];
  __syncthreads();
  const float* base = in + (long)b * 98304 + (long)d * 16;
  float acc = 0.f;
  for (int t = 0; t < 48; ++t) {
    const float4* p = (const float4*)(base + (long)t * 2048);
    float4 v0 = p[0], v1 = p[1], v2 = p[2], v3 = p[3];
    acc += v0.x * wx[t]       + v0.y * wx[48 + t]  + v0.z * wx[96 + t]  + v0.w * wx[144 + t];
    acc += v1.x * wx[192 + t] + v1.y * wx[240 + t] + v1.z * wx[288 + t] + v1.w * wx[336 + t];
    acc += v2.x * wx[384 + t] + v2.y * wx[432 + t] + v2.z * wx[480 + t] + v2.w * wx[528 + t];
    acc += v3.x * wx[576 + t] + v3.y * wx[624 + t] + v3.z * wx[672 + t] + v3.w * wx[720 + t];
  }
  acc += attn_b[0];
  red[d] = acc;
  __syncthreads();
  for (int s = 64; s > 0; s >>= 1) {
    if (d < s) red[d] = fmaxf(red[d], red[d + s]);
    __syncthreads();
  }
  float mx = red[0];
  __syncthreads();
  float ex = expf(acc - mx);
  red[d] = ex;
  __syncthreads();
  for (int s = 64; s > 0; s >>= 1) {
    if (d < s) red[d] += red[d + s];
    __syncthreads();
  }
  a_out[b * 128 + d] = ex / red[0];
}

// ---------------- K_xhat: x_hat[t*512+b][d*16+f] = a[b,d]*x[b,t,d,f] (bf16)
__global__ __launch_bounds__(256) void k_xhat(const float* __restrict__ in,
                                              const float* __restrict__ a,
                                              unsigned short* __restrict__ xh) {
  const int mrow = blockIdx.x;            // t*512 + b
  const int t = mrow >> 9, b = mrow & 511;
  const int tid = threadIdx.x;
  const int k = tid * 8;
  const int d = k >> 4;
  const int f0 = k & 15;
  const float* src = in + (((long)(b * 48 + t) * 128 + d) * 16 + f0);
  float4 v0 = *(const float4*)src;
  float4 v1 = *(const float4*)(src + 4);
  float s = a[b * 128 + d];
  u16x8 o;
  o[0] = f2bf(v0.x * s); o[1] = f2bf(v0.y * s); o[2] = f2bf(v0.z * s); o[3] = f2bf(v0.w * s);
  o[4] = f2bf(v1.x * s); o[5] = f2bf(v1.y * s); o[6] = f2bf(v1.z * s); o[7] = f2bf(v1.w * s);
  *(u16x8*)(xh + (long)mrow * 2048 + k) = o;
}

// ---------------- K_gemm: gates_x = x_hat @ w_ih^T  (bf16 MFMA, 128x128 tiles)
__global__ __launch_bounds__(256) void k_gemm(const unsigned short* __restrict__ A,
                                              const unsigned short* __restrict__ Bw,
                                              unsigned short* __restrict__ C) {
  __shared__ unsigned short Asm[128 * 64];
  __shared__ unsigned short Bsm[128 * 64];
  const int tid = threadIdx.x;
  const int wave = tid >> 6, lane = tid & 63;
  const int q = lane >> 4, l16 = lane & 15;
  const long m0 = (long)blockIdx.y * 128;
  const long n0 = (long)blockIdx.x * 128;
  const int wm = wave & 1, wn = wave >> 1;
  f32x4 acc[4][4];
  f32x4 zz = {0.f, 0.f, 0.f, 0.f};
#pragma unroll
  for (int i = 0; i < 4; ++i)
#pragma unroll
    for (int j = 0; j < 4; ++j) acc[i][j] = zz;
  const int srow = wave * 32 + (lane >> 3);
  const int scol = (lane & 7) * 8;
  const unsigned short* Ag = A + (m0 + srow) * 2048 + scol;
  const unsigned short* Bg = Bw + (n0 + srow) * 2048 + scol;
  for (int kt = 0; kt < 32; ++kt) {
    __syncthreads();
#pragma unroll
    for (int i = 0; i < 4; ++i) {
      g2lds16(Ag + (long)kt * 64 + (long)i * 8 * 2048, Asm + (wave * 32 + i * 8) * 64);
      g2lds16(Bg + (long)kt * 64 + (long)i * 8 * 2048, Bsm + (wave * 32 + i * 8) * 64);
    }
    asm volatile("s_waitcnt vmcnt(0)" ::: "memory");
    __syncthreads();
#pragma unroll
    for (int ks = 0; ks < 64; ks += 32) {
      s16x8 af[4], bv[4];
#pragma unroll
      for (int mt = 0; mt < 4; ++mt)
        af[mt] = *(const s16x8*)&Asm[(wm * 64 + mt * 16 + l16) * 64 + ks + q * 8];
#pragma unroll
      for (int nt = 0; nt < 4; ++nt)
        bv[nt] = *(const s16x8*)&Bsm[(wn * 64 + nt * 16 + l16) * 64 + ks + q * 8];
#pragma unroll
      for (int mt = 0; mt < 4; ++mt)
#pragma unroll
        for (int nt = 0; nt < 4; ++nt)
          acc[mt][nt] = __builtin_amdgcn_mfma_f32_16x16x32_bf16(af[mt], bv[nt], acc[mt][nt], 0, 0, 0);
    }
  }
#pragma unroll
  for (int mt = 0; mt < 4; ++mt)
#pragma unroll
    for (int nt = 0; nt < 4; ++nt)
#pragma unroll
      for (int r = 0; r < 4; ++r) {
        long m = m0 + wm * 64 + mt * 16 + q * 4 + r;
        long n = n0 + wn * 64 + nt * 16 + l16;
        C[m * 2048 + n] = f2bf(acc[mt][nt][r]);
      }
}

// ---------------- K_rec: persistent LSTM scan -----------------------------
// block (bt,g): bt = blockIdx&15 (same-XCD group heuristic), g = blockIdx>>4.
// Owns batch rows [bt*32,+32), h-cols [g*32,+32) (gate cols q*512+g*32+r).
// w_hh fragments live in REGISTERS (loaded once). h double-buffered.
// Barrier: per-block stamp slot (release store), 16 lanes poll 16 slots.
__global__ __launch_bounds__(256, 1) void k_rec(const unsigned short* __restrict__ gx,
                                                const unsigned short* __restrict__ whh_b,
                                                const float* __restrict__ b_ih,
                                                const float* __restrict__ b_hh,
                                                unsigned short* __restrict__ h_buf,
                                                float* __restrict__ out,
                                                unsigned int* __restrict__ bar) {
  __shared__ float gsm[4 * 32 * 36];     // [quad][colN 32][rowM pad36]
  const int tid = threadIdx.x;
  const int wave = tid >> 6, lane = tid & 63;   // wave == gate quadrant
  const int q = lane >> 4, l16 = lane & 15;
  const int bt = blockIdx.x & 15, g = blockIdx.x >> 4;
  const int b0 = bt * 32;
  const int pm = tid >> 3, pr = (tid & 7) * 4;  // pointwise: row pm, cols pr..pr+3
  unsigned int* slots = &bar[bt * 16];          // 16 slots, 64B line per group

  // w_hh fragments -> registers: wreg[nt*16+kk] = row (wave*512+g*32+nt*16+l16), k kk*32+q*8
  s16x8 wreg[32];
#pragma unroll
  for (int nt = 0; nt < 2; ++nt) {
    const unsigned short* wp = whh_b + (long)(wave * 512 + g * 32 + nt * 16 + l16) * 512 + q * 8;
#pragma unroll
    for (int kk = 0; kk < 16; ++kk)
      wreg[nt * 16 + kk] = *(const s16x8*)(wp + kk * 32);
  }
  // bias in registers (pointwise layout)
  float bias_[16];
#pragma unroll
  for (int qq = 0; qq < 4; ++qq)
#pragma unroll
    for (int rr = 0; rr < 4; ++rr) {
      int j = qq * 512 + g * 32 + pr + rr;
      bias_[qq * 4 + rr] = b_ih[j] + b_hh[j];
    }
  float creg[4] = {0.f, 0.f, 0.f, 0.f};
  const f32x4 zz = {0.f, 0.f, 0.f, 0.f};

  for (int t = 0; t < 48; ++t) {
    // prefetch gx (independent of barrier)
    u16x4 gxr[4];
    const unsigned short* gp = gx + ((long)t * 512 + b0 + pm) * 2048 + g * 32 + pr;
#pragma unroll
    for (int qq = 0; qq < 4; ++qq) gxr[qq] = *(const u16x4*)(gp + qq * 512);

    f32x4 acc[2][2] = {{zz, zz}, {zz, zz}};
    if (t > 0) {
      // wait: 16 lanes poll 16 slots (relaxed), acquire once on exit
      if (wave == 0 && lane < 16) {
        while (__hip_atomic_load(&slots[lane], __ATOMIC_RELAXED, __HIP_MEMORY_SCOPE_AGENT) < (unsigned)t)
          __builtin_amdgcn_s_sleep(1);
        (void)__hip_atomic_load(&slots[lane], __ATOMIC_ACQUIRE, __HIP_MEMORY_SCOPE_AGENT);
      }
      __syncthreads();
      const unsigned short* hprev = h_buf + ((t - 1) & 1) * (512 * 512);
#pragma unroll
      for (int kk = 0; kk < 16; ++kk) {
        s16x8 af0 = *(const s16x8*)&hprev[(b0 + l16) * 512 + kk * 32 + q * 8];
        s16x8 af1 = *(const s16x8*)&hprev[(b0 + 16 + l16) * 512 + kk * 32 + q * 8];
        acc[0][0] = __builtin_amdgcn_mfma_f32_16x16x32_bf16(af0, wreg[kk],      acc[0][0], 0, 0, 0);
        acc[0][1] = __builtin_amdgcn_mfma_f32_16x16x32_bf16(af0, wreg[16 + kk], acc[0][1], 0, 0, 0);
        acc[1][0] = __builtin_amdgcn_mfma_f32_16x16x32_bf16(af1, wreg[kk],      acc[1][0], 0, 0, 0);
        acc[1][1] = __builtin_amdgcn_mfma_f32_16x16x32_bf16(af1, wreg[16 + kk], acc[1][1], 0, 0, 0);
      }
    }
    // acc -> gsm[wave][colN][rowM]; rows mt*16+q*4..+3 contiguous => b128 store
#pragma unroll
    for (int mt = 0; mt < 2; ++mt)
#pragma unroll
      for (int nt = 0; nt < 2; ++nt)
        *(f32x4*)&gsm[(wave * 32 + nt * 16 + l16) * 36 + mt * 16 + q * 4] = acc[mt][nt];
    __syncthreads();
    // pointwise LSTM cell: thread owns (row b0+pm, cols g*32+pr..+3)
    float hval[4];
#pragma unroll
    for (int rr = 0; rr < 4; ++rr) {
      float gv[4];
#pragma unroll
      for (int qq = 0; qq < 4; ++qq)
        gv[qq] = gsm[(qq * 32 + pr + rr) * 36 + pm] + bf2f(gxr[qq][rr]) + bias_[qq * 4 + rr];
      float is = sigmoidf_(gv[0]);
      float fs = sigmoidf_(gv[1]);
      float gt = tanhf(gv[2]);
      float os = sigmoidf_(gv[3]);
      creg[rr] = fs * creg[rr] + is * gt;
      hval[rr] = os * tanhf(creg[rr]);
    }
    u16x4 hb = {f2bf(hval[0]), f2bf(hval[1]), f2bf(hval[2]), f2bf(hval[3])};
    *(u16x4*)&h_buf[(t & 1) * (512 * 512) + (b0 + pm) * 512 + g * 32 + pr] = hb;
    f32x4 ov = {hval[0], hval[1], hval[2], hval[3]};
    __builtin_nontemporal_store(ov, (f32x4*)&out[(long)(b0 + pm) * (T_ * H_) + (long)t * H_ + g * 32 + pr]);
    __syncthreads();   // drains all waves' stores (vmcnt0 before s_barrier)
    if (t < 47 && tid == 0)
      __hip_atomic_store(&slots[g], (unsigned)(t + 1), __ATOMIC_RELEASE, __HIP_MEMORY_SCOPE_AGENT);
  }
}

extern "C" void kernel_launch(void* const* d_in, const int* in_sizes, int n_in,
                              void* d_out, int out_size, void* d_ws, size_t ws_size,
                              hipStream_t stream) {
  const float* input  = (const float*)d_in[0];
  const float* attn_w = (const float*)d_in[1];
  const float* attn_b = (const float*)d_in[2];
  const float* w_ih   = (const float*)d_in[3];
  const float* w_hh   = (const float*)d_in[4];
  const float* b_ih   = (const float*)d_in[5];
  const float* b_hh   = (const float*)d_in[6];
  float* out = (float*)d_out;

  char* ws = (char*)d_ws;
  unsigned int* bar     = (unsigned int*)ws;                   // [0, 1024)
  float* a_ws           = (float*)(ws + 1024);                 // 512*128*4    = 262144
  unsigned short* h_buf = (unsigned short*)(ws + 263168);      // 2*512*512*2  = 1048576
  unsigned short* whh_b = (unsigned short*)(ws + 1311744);     // 2048*512*2   = 2097152
  unsigned short* wih_b = (unsigned short*)(ws + 3408896);     // 2048*2048*2  = 8388608
  unsigned short* x_hat = (unsigned short*)(ws + 11797504);    // 24576*2048*2 = 100663296
  unsigned short* gxws  = (unsigned short*)(ws + 112460800);   // 24576*2048*2 = 100663296

  (void)hipMemsetAsync(d_ws, 0, 1024, stream);
  hipLaunchKernelGGL(k_prep, dim3(5120), dim3(256), 0, stream, w_ih, w_hh, wih_b, whh_b);
  hipLaunchKernelGGL(k_ex, dim3(512), dim3(128), 0, stream, input, attn_w, attn_b, a_ws);
  hipLaunchKernelGGL(k_xhat, dim3(24576), dim3(256), 0, stream, input, a_ws, x_hat);
  hipLaunchKernelGGL(k_gemm, dim3(16, 192), dim3(256), 0, stream, x_hat, wih_b, gxws);
  hipLaunchKernelGGL(k_rec, dim3(256), dim3(256), 0, stream, gxws, whh_b, b_ih, b_hh, h_buf, out, bar);
}

// Round 4
// 795.452 us; speedup vs baseline: 3.4267x; 1.6146x over previous
//
#include <hip/hip_runtime.h>

#define B_ 512
#define T_ 48
#define D_ 128
#define F_ 16
#define H_ 512
// K = D_*F_ = 2048, gates = 4*H_ = 2048, M = T_*B_ = 24576

typedef float f32x4 __attribute__((ext_vector_type(4)));
typedef short s16x8 __attribute__((ext_vector_type(8)));
typedef unsigned short u16x8 __attribute__((ext_vector_type(8)));
typedef unsigned short u16x4 __attribute__((ext_vector_type(4)));
typedef unsigned long long u64;

__device__ __forceinline__ unsigned short f2bf(float x) {
  unsigned u = __float_as_uint(x);
  u += 0x7fffu + ((u >> 16) & 1u);   // round-to-nearest-even
  return (unsigned short)(u >> 16);
}
__device__ __forceinline__ float bf2f(unsigned short h) {
  return __uint_as_float(((unsigned)h) << 16);
}
__device__ __forceinline__ float sigmoidf_(float x) {
  return 1.f / (1.f + expf(-x));
}

// Relaxed system-scope (sc0 sc1) accesses: bypass L1/L2, coherent at L3.
// No acquire/release -> no buffer_inv / buffer_wbl2 cache nukes.
__device__ __forceinline__ void st_sys_u64(u64* p, u64 v) {
  __hip_atomic_store(p, v, __ATOMIC_RELAXED, __HIP_MEMORY_SCOPE_SYSTEM);
}
__device__ __forceinline__ u64 ld_sys_u64(const u64* p) {
  return __hip_atomic_load((u64*)p, __ATOMIC_RELAXED, __HIP_MEMORY_SCOPE_SYSTEM);
}
__device__ __forceinline__ void st_sys_u32(unsigned* p, unsigned v) {
  __hip_atomic_store(p, v, __ATOMIC_RELAXED, __HIP_MEMORY_SCOPE_SYSTEM);
}
__device__ __forceinline__ unsigned ld_sys_u32(const unsigned* p) {
  return __hip_atomic_load((unsigned*)p, __ATOMIC_RELAXED, __HIP_MEMORY_SCOPE_SYSTEM);
}

#define AS1 __attribute__((address_space(1)))
#define AS3 __attribute__((address_space(3)))
__device__ __forceinline__ void g2lds16(const void* g, void* l) {
  __builtin_amdgcn_global_load_lds((const AS1 void*)g, (AS3 void*)l, 16, 0, 0);
}

// ---------------- K_prep: fp32 -> bf16 weight conversion ----------------
__global__ __launch_bounds__(256) void k_prep(const float* __restrict__ wih,
                                              const float* __restrict__ whh,
                                              unsigned short* __restrict__ wih_b,
                                              unsigned short* __restrict__ whh_b) {
  long i4 = ((long)blockIdx.x * 256 + threadIdx.x) * 4;
  if (i4 < 4194304) {
    float4 v = *(const float4*)(wih + i4);
    u16x4 o = {f2bf(v.x), f2bf(v.y), f2bf(v.z), f2bf(v.w)};
    *(u16x4*)(wih_b + i4) = o;
  } else {
    long j = i4 - 4194304;
    if (j < 1048576) {
      float4 v = *(const float4*)(whh + j);
      u16x4 o = {f2bf(v.x), f2bf(v.y), f2bf(v.z), f2bf(v.w)};
      *(u16x4*)(whh_b + j) = o;
    }
  }
}

// ---------------- K_ex: e_x = x_flat @ w_x + b, then softmax over D -----
__global__ __launch_bounds__(128) void k_ex(const float* __restrict__ in,
                                            const float* __restrict__ attn_w,
                                            const float* __restrict__ attn_b,
                                            float* __restrict__ a_out) {
  __shared__ float wx[768];
  __shared__ float red[128];
  const int b = blockIdx.x, d = threadIdx.x;
  for (int i = d; i < 768; i += 128) wx[i] = attn_w[1024 + i];
  __syncthreads();
  const float* base = in + (long)b * 98304 + (long)d * 16;
  float acc = 0.f;
  for (int t = 0; t < 48; ++t) {
    const float4* p = (const float4*)(base + (long)t * 2048);
    float4 v0 = p[0], v1 = p[1], v2 = p[2], v3 = p[3];
    acc += v0.x * wx[t]       + v0.y * wx[48 + t]  + v0.z * wx[96 + t]  + v0.w * wx[144 + t];
    acc += v1.x * wx[192 + t] + v1.y * wx[240 + t] + v1.z * wx[288 + t] + v1.w * wx[336 + t];
    acc += v2.x * wx[384 + t] + v2.y * wx[432 + t] + v2.z * wx[480 + t] + v2.w * wx[528 + t];
    acc += v3.x * wx[576 + t] + v3.y * wx[624 + t] + v3.z * wx[672 + t] + v3.w * wx[720 + t];
  }
  acc += attn_b[0];
  red[d] = acc;
  __syncthreads();
  for (int s = 64; s > 0; s >>= 1) {
    if (d < s) red[d] = fmaxf(red[d], red[d + s]);
    __syncthreads();
  }
  float mx = red[0];
  __syncthreads();
  float ex = expf(acc - mx);
  red[d] = ex;
  __syncthreads();
  for (int s = 64; s > 0; s >>= 1) {
    if (d < s) red[d] += red[d + s];
    __syncthreads();
  }
  a_out[b * 128 + d] = ex / red[0];
}

// ---------------- K_xhat: x_hat[t*512+b][d*16+f] = a[b,d]*x[b,t,d,f] (bf16)
__global__ __launch_bounds__(256) void k_xhat(const float* __restrict__ in,
                                              const float* __restrict__ a,
                                              unsigned short* __restrict__ xh) {
  const int mrow = blockIdx.x;            // t*512 + b
  const int t = mrow >> 9, b = mrow & 511;
  const int tid = threadIdx.x;
  const int k = tid * 8;
  const int d = k >> 4;
  const int f0 = k & 15;
  const float* src = in + (((long)(b * 48 + t) * 128 + d) * 16 + f0);
  float4 v0 = *(const float4*)src;
  float4 v1 = *(const float4*)(src + 4);
  float s = a[b * 128 + d];
  u16x8 o;
  o[0] = f2bf(v0.x * s); o[1] = f2bf(v0.y * s); o[2] = f2bf(v0.z * s); o[3] = f2bf(v0.w * s);
  o[4] = f2bf(v1.x * s); o[5] = f2bf(v1.y * s); o[6] = f2bf(v1.z * s); o[7] = f2bf(v1.w * s);
  *(u16x8*)(xh + (long)mrow * 2048 + k) = o;
}

// ---------------- K_gemm: gates_x = x_hat @ w_ih^T  (bf16 MFMA, 128x128 tiles)
__global__ __launch_bounds__(256) void k_gemm(const unsigned short* __restrict__ A,
                                              const unsigned short* __restrict__ Bw,
                                              unsigned short* __restrict__ C) {
  __shared__ unsigned short Asm[128 * 64];
  __shared__ unsigned short Bsm[128 * 64];
  const int tid = threadIdx.x;
  const int wave = tid >> 6, lane = tid & 63;
  const int q = lane >> 4, l16 = lane & 15;
  const long m0 = (long)blockIdx.y * 128;
  const long n0 = (long)blockIdx.x * 128;
  const int wm = wave & 1, wn = wave >> 1;
  f32x4 acc[4][4];
  f32x4 zz = {0.f, 0.f, 0.f, 0.f};
#pragma unroll
  for (int i = 0; i < 4; ++i)
#pragma unroll
    for (int j = 0; j < 4; ++j) acc[i][j] = zz;
  const int srow = wave * 32 + (lane >> 3);
  const int scol = (lane & 7) * 8;
  const unsigned short* Ag = A + (m0 + srow) * 2048 + scol;
  const unsigned short* Bg = Bw + (n0 + srow) * 2048 + scol;
  for (int kt = 0; kt < 32; ++kt) {
    __syncthreads();
#pragma unroll
    for (int i = 0; i < 4; ++i) {
      g2lds16(Ag + (long)kt * 64 + (long)i * 8 * 2048, Asm + (wave * 32 + i * 8) * 64);
      g2lds16(Bg + (long)kt * 64 + (long)i * 8 * 2048, Bsm + (wave * 32 + i * 8) * 64);
    }
    asm volatile("s_waitcnt vmcnt(0)" ::: "memory");
    __syncthreads();
#pragma unroll
    for (int ks = 0; ks < 64; ks += 32) {
      s16x8 af[4], bv[4];
#pragma unroll
      for (int mt = 0; mt < 4; ++mt)
        af[mt] = *(const s16x8*)&Asm[(wm * 64 + mt * 16 + l16) * 64 + ks + q * 8];
#pragma unroll
      for (int nt = 0; nt < 4; ++nt)
        bv[nt] = *(const s16x8*)&Bsm[(wn * 64 + nt * 16 + l16) * 64 + ks + q * 8];
#pragma unroll
      for (int mt = 0; mt < 4; ++mt)
#pragma unroll
        for (int nt = 0; nt < 4; ++nt)
          acc[mt][nt] = __builtin_amdgcn_mfma_f32_16x16x32_bf16(af[mt], bv[nt], acc[mt][nt], 0, 0, 0);
    }
  }
#pragma unroll
  for (int mt = 0; mt < 4; ++mt)
#pragma unroll
    for (int nt = 0; nt < 4; ++nt)
#pragma unroll
      for (int r = 0; r < 4; ++r) {
        long m = m0 + wm * 64 + mt * 16 + q * 4 + r;
        long n = n0 + wn * 64 + nt * 16 + l16;
        C[m * 2048 + n] = f2bf(acc[mt][nt][r]);
      }
}

// ---------------- K_rec: persistent LSTM scan -----------------------------
// block (bt,g): bt = blockIdx&15, g = blockIdx>>4. Owns batch rows
// [bt*32,+32), h-cols [g*32,+32) (gate cols q*512+g*32+r).
// w_hh fragments PINNED in VGPRs (asm anti-remat). h(t-1) staged once per
// step into LDS via system-scope (sc0 sc1) loads; flags via system-scope
// relaxed stores after __syncthreads' vmcnt(0) drain. NO acquire/release ->
// no L2 writeback/invalidate; placement-independent via coherent L3.
__global__ __launch_bounds__(256, 1) void k_rec(const unsigned short* __restrict__ gx,
                                                const unsigned short* __restrict__ whh_b,
                                                const float* __restrict__ b_ih,
                                                const float* __restrict__ b_hh,
                                                unsigned short* __restrict__ h_buf,
                                                float* __restrict__ out,
                                                unsigned int* __restrict__ bar) {
  __shared__ unsigned short hs[32 * 528];   // h(t-1) stage, rows padded to 528
  __shared__ float gsm[4 * 32 * 36];        // [quad][colN 32][rowM pad36]
  const int tid = threadIdx.x;
  const int wave = tid >> 6, lane = tid & 63;   // wave == gate quadrant
  const int q = lane >> 4, l16 = lane & 15;
  const int bt = blockIdx.x & 15, g = blockIdx.x >> 4;
  const int b0 = bt * 32;
  const int pm = tid >> 3, pr = (tid & 7) * 4;  // pointwise: row pm, cols pr..pr+3
  const int srow = tid >> 3, st7 = tid & 7;     // stage: row srow, ull lane st7
  unsigned int* slots = &bar[bt * 16];

  // w_hh fragments -> registers (once), pinned against rematerialization
  s16x8 wreg[32];
#pragma unroll
  for (int nt = 0; nt < 2; ++nt) {
    const unsigned short* wp = whh_b + (long)(wave * 512 + g * 32 + nt * 16 + l16) * 512 + q * 8;
#pragma unroll
    for (int kk = 0; kk < 16; ++kk)
      wreg[nt * 16 + kk] = *(const s16x8*)(wp + kk * 32);
  }
#pragma unroll
  for (int i = 0; i < 32; ++i) asm volatile("" : "+v"(wreg[i]));

  float bias_[16];
#pragma unroll
  for (int qq = 0; qq < 4; ++qq)
#pragma unroll
    for (int rr = 0; rr < 4; ++rr) {
      int j = qq * 512 + g * 32 + pr + rr;
      bias_[qq * 4 + rr] = b_ih[j] + b_hh[j];
    }
  float creg[4] = {0.f, 0.f, 0.f, 0.f};
  const f32x4 zz = {0.f, 0.f, 0.f, 0.f};

  for (int t = 0; t < 48; ++t) {
    // prefetch gx (plain cached loads; read-only, L2 stays warm now)
    u16x4 gxr[4];
    const unsigned short* gp = gx + ((long)t * 512 + b0 + pm) * 2048 + g * 32 + pr;
#pragma unroll
    for (int qq = 0; qq < 4; ++qq) gxr[qq] = *(const u16x4*)(gp + qq * 512);

    f32x4 acc[2][2] = {{zz, zz}, {zz, zz}};
    if (t > 0) {
      // wait for the 16 producer slots of this bt group (relaxed sys polls)
      if (wave == 0 && lane < 16) {
        while (ld_sys_u32(&slots[lane]) < (unsigned)t)
          __builtin_amdgcn_s_sleep(1);
      }
      __syncthreads();
      // stage h(t-1)[b0:b0+32, 0:512] -> LDS (sys loads bypass stale L1/L2)
      const u64* hp = (const u64*)(h_buf + ((t - 1) & 1) * (512 * 512) + (long)b0 * 512);
      u64 tmp[16];
#pragma unroll
      for (int j = 0; j < 16; ++j)
        tmp[j] = ld_sys_u64(hp + (long)srow * 128 + st7 + 8 * j);
#pragma unroll
      for (int j = 0; j < 16; ++j)
        *(u64*)&hs[srow * 528 + (st7 + 8 * j) * 4] = tmp[j];
      __syncthreads();
#pragma unroll
      for (int kk = 0; kk < 16; ++kk) {
        s16x8 af0 = *(const s16x8*)&hs[l16 * 528 + kk * 32 + q * 8];
        s16x8 af1 = *(const s16x8*)&hs[(16 + l16) * 528 + kk * 32 + q * 8];
        acc[0][0] = __builtin_amdgcn_mfma_f32_16x16x32_bf16(af0, wreg[kk],      acc[0][0], 0, 0, 0);
        acc[0][1] = __builtin_amdgcn_mfma_f32_16x16x32_bf16(af0, wreg[16 + kk], acc[0][1], 0, 0, 0);
        acc[1][0] = __builtin_amdgcn_mfma_f32_16x16x32_bf16(af1, wreg[kk],      acc[1][0], 0, 0, 0);
        acc[1][1] = __builtin_amdgcn_mfma_f32_16x16x32_bf16(af1, wreg[16 + kk], acc[1][1], 0, 0, 0);
      }
    }
    // acc -> gsm[wave][colN][rowM]; rows mt*16+q*4..+3 contiguous => b128 store
#pragma unroll
    for (int mt = 0; mt < 2; ++mt)
#pragma unroll
      for (int nt = 0; nt < 2; ++nt)
        *(f32x4*)&gsm[(wave * 32 + nt * 16 + l16) * 36 + mt * 16 + q * 4] = acc[mt][nt];
    __syncthreads();
    // pointwise LSTM cell: thread owns (row b0+pm, cols g*32+pr..+3)
    float hval[4];
#pragma unroll
    for (int rr = 0; rr < 4; ++rr) {
      float gv[4];
#pragma unroll
      for (int qq = 0; qq < 4; ++qq)
        gv[qq] = gsm[(qq * 32 + pr + rr) * 36 + pm] + bf2f(gxr[qq][rr]) + bias_[qq * 4 + rr];
      float is = sigmoidf_(gv[0]);
      float fs = sigmoidf_(gv[1]);
      float gt = tanhf(gv[2]);
      float os = sigmoidf_(gv[3]);
      creg[rr] = fs * creg[rr] + is * gt;
      hval[rr] = os * tanhf(creg[rr]);
    }
    // publish h slice via system-scope stores (land in coherent L3)
    u16x4 hb = {f2bf(hval[0]), f2bf(hval[1]), f2bf(hval[2]), f2bf(hval[3])};
    u64 hb8;
    __builtin_memcpy(&hb8, &hb, 8);
    st_sys_u64((u64*)&h_buf[(t & 1) * (512 * 512) + (b0 + pm) * 512 + g * 32 + pr], hb8);
    f32x4 ov = {hval[0], hval[1], hval[2], hval[3]};
    __builtin_nontemporal_store(ov, (f32x4*)&out[(long)(b0 + pm) * (T_ * H_) + (long)t * H_ + g * 32 + pr]);
    __syncthreads();   // drains vmcnt(0): h stores at L3 before flag
    if (t < 47 && tid == 0)
      st_sys_u32(&slots[g], (unsigned)(t + 1));
  }
}

extern "C" void kernel_launch(void* const* d_in, const int* in_sizes, int n_in,
                              void* d_out, int out_size, void* d_ws, size_t ws_size,
                              hipStream_t stream) {
  const float* input  = (const float*)d_in[0];
  const float* attn_w = (const float*)d_in[1];
  const float* attn_b = (const float*)d_in[2];
  const float* w_ih   = (const float*)d_in[3];
  const float* w_hh   = (const float*)d_in[4];
  const float* b_ih   = (const float*)d_in[5];
  const float* b_hh   = (const float*)d_in[6];
  float* out = (float*)d_out;

  char* ws = (char*)d_ws;
  unsigned int* bar     = (unsigned int*)ws;                   // [0, 1024)
  float* a_ws           = (float*)(ws + 1024);                 // 512*128*4    = 262144
  unsigned short* h_buf = (unsigned short*)(ws + 263168);      // 2*512*512*2  = 1048576
  unsigned short* whh_b = (unsigned short*)(ws + 1311744);     // 2048*512*2   = 2097152
  unsigned short* wih_b = (unsigned short*)(ws + 3408896);     // 2048*2048*2  = 8388608
  unsigned short* x_hat = (unsigned short*)(ws + 11797504);    // 24576*2048*2 = 100663296
  unsigned short* gxws  = (unsigned short*)(ws + 112460800);   // 24576*2048*2 = 100663296

  (void)hipMemsetAsync(d_ws, 0, 1024, stream);
  hipLaunchKernelGGL(k_prep, dim3(5120), dim3(256), 0, stream, w_ih, w_hh, wih_b, whh_b);
  hipLaunchKernelGGL(k_ex, dim3(512), dim3(128), 0, stream, input, attn_w, attn_b, a_ws);
  hipLaunchKernelGGL(k_xhat, dim3(24576), dim3(256), 0, stream, input, a_ws, x_hat);
  hipLaunchKernelGGL(k_gemm, dim3(16, 192), dim3(256), 0, stream, x_hat, wih_b, gxws);
  hipLaunchKernelGGL(k_rec, dim3(256), dim3(256), 0, stream, gxws, whh_b, b_ih, b_hh, h_buf, out, bar);
}

// Round 5
// 775.511 us; speedup vs baseline: 3.5148x; 1.0257x over previous
//
#include <hip/hip_runtime.h>

#define B_ 512
#define T_ 48
#define D_ 128
#define F_ 16
#define H_ 512
// K = D_*F_ = 2048, gates = 4*H_ = 2048, M = T_*B_ = 24576

typedef float f32x4 __attribute__((ext_vector_type(4)));
typedef short s16x8 __attribute__((ext_vector_type(8)));
typedef unsigned short u16x8 __attribute__((ext_vector_type(8)));
typedef unsigned short u16x4 __attribute__((ext_vector_type(4)));
typedef unsigned long long u64;

__device__ __forceinline__ unsigned short f2bf(float x) {
  unsigned u = __float_as_uint(x);
  u += 0x7fffu + ((u >> 16) & 1u);   // round-to-nearest-even
  return (unsigned short)(u >> 16);
}
__device__ __forceinline__ float bf2f(unsigned short h) {
  return __uint_as_float(((unsigned)h) << 16);
}
__device__ __forceinline__ float sigmoidf_(float x) {
  return 1.f / (1.f + expf(-x));
}

// Relaxed system-scope (sc0 sc1) accesses: bypass L1/L2, coherent at L3.
// No acquire/release -> no buffer_inv / buffer_wbl2 cache nukes.
__device__ __forceinline__ void st_sys_u64(u64* p, u64 v) {
  __hip_atomic_store(p, v, __ATOMIC_RELAXED, __HIP_MEMORY_SCOPE_SYSTEM);
}
__device__ __forceinline__ u64 ld_sys_u64(const u64* p) {
  return __hip_atomic_load((u64*)p, __ATOMIC_RELAXED, __HIP_MEMORY_SCOPE_SYSTEM);
}
__device__ __forceinline__ void st_sys_u32(unsigned* p, unsigned v) {
  __hip_atomic_store(p, v, __ATOMIC_RELAXED, __HIP_MEMORY_SCOPE_SYSTEM);
}
__device__ __forceinline__ unsigned ld_sys_u32(const unsigned* p) {
  return __hip_atomic_load((unsigned*)p, __ATOMIC_RELAXED, __HIP_MEMORY_SCOPE_SYSTEM);
}

#define AS1 __attribute__((address_space(1)))
#define AS3 __attribute__((address_space(3)))
__device__ __forceinline__ void g2lds16(const void* g, void* l) {
  __builtin_amdgcn_global_load_lds((const AS1 void*)g, (AS3 void*)l, 16, 0, 0);
}

// ---------------- K_prep: fp32 -> bf16 weight conversion ----------------
__global__ __launch_bounds__(256) void k_prep(const float* __restrict__ wih,
                                              const float* __restrict__ whh,
                                              unsigned short* __restrict__ wih_b,
                                              unsigned short* __restrict__ whh_b) {
  long i4 = ((long)blockIdx.x * 256 + threadIdx.x) * 4;
  if (i4 < 4194304) {
    float4 v = *(const float4*)(wih + i4);
    u16x4 o = {f2bf(v.x), f2bf(v.y), f2bf(v.z), f2bf(v.w)};
    *(u16x4*)(wih_b + i4) = o;
  } else {
    long j = i4 - 4194304;
    if (j < 1048576) {
      float4 v = *(const float4*)(whh + j);
      u16x4 o = {f2bf(v.x), f2bf(v.y), f2bf(v.z), f2bf(v.w)};
      *(u16x4*)(whh_b + j) = o;
    }
  }
}

// ---------------- K_ex: e_x = x_flat @ w_x + b, then softmax over D -----
__global__ __launch_bounds__(128) void k_ex(const float* __restrict__ in,
                                            const float* __restrict__ attn_w,
                                            const float* __restrict__ attn_b,
                                            float* __restrict__ a_out) {
  __shared__ float wx[768];
  __shared__ float red[128];
  const int b = blockIdx.x, d = threadIdx.x;
  for (int i = d; i < 768; i += 128) wx[i] = attn_w[1024 + i];
  __syncthreads();
  const float* base = in + (long)b * 98304 + (long)d * 16;
  float acc = 0.f;
  for (int t = 0; t < 48; ++t) {
    const float4* p = (const float4*)(base + (long)t * 2048);
    float4 v0 = p[0], v1 = p[1], v2 = p[2], v3 = p[3];
    acc += v0.x * wx[t]       + v0.y * wx[48 + t]  + v0.z * wx[96 + t]  + v0.w * wx[144 + t];
    acc += v1.x * wx[192 + t] + v1.y * wx[240 + t] + v1.z * wx[288 + t] + v1.w * wx[336 + t];
    acc += v2.x * wx[384 + t] + v2.y * wx[432 + t] + v2.z * wx[480 + t] + v2.w * wx[528 + t];
    acc += v3.x * wx[576 + t] + v3.y * wx[624 + t] + v3.z * wx[672 + t] + v3.w * wx[720 + t];
  }
  acc += attn_b[0];
  red[d] = acc;
  __syncthreads();
  for (int s = 64; s > 0; s >>= 1) {
    if (d < s) red[d] = fmaxf(red[d], red[d + s]);
    __syncthreads();
  }
  float mx = red[0];
  __syncthreads();
  float ex = expf(acc - mx);
  red[d] = ex;
  __syncthreads();
  for (int s = 64; s > 0; s >>= 1) {
    if (d < s) red[d] += red[d + s];
    __syncthreads();
  }
  a_out[b * 128 + d] = ex / red[0];
}

// ---------------- K_xhat: x_hat[t*512+b][d*16+f] = a[b,d]*x[b,t,d,f] (bf16)
__global__ __launch_bounds__(256) void k_xhat(const float* __restrict__ in,
                                              const float* __restrict__ a,
                                              unsigned short* __restrict__ xh) {
  const int mrow = blockIdx.x;            // t*512 + b
  const int t = mrow >> 9, b = mrow & 511;
  const int tid = threadIdx.x;
  const int k = tid * 8;
  const int d = k >> 4;
  const int f0 = k & 15;
  const float* src = in + (((long)(b * 48 + t) * 128 + d) * 16 + f0);
  float4 v0 = *(const float4*)src;
  float4 v1 = *(const float4*)(src + 4);
  float s = a[b * 128 + d];
  u16x8 o;
  o[0] = f2bf(v0.x * s); o[1] = f2bf(v0.y * s); o[2] = f2bf(v0.z * s); o[3] = f2bf(v0.w * s);
  o[4] = f2bf(v1.x * s); o[5] = f2bf(v1.y * s); o[6] = f2bf(v1.z * s); o[7] = f2bf(v1.w * s);
  *(u16x8*)(xh + (long)mrow * 2048 + k) = o;
}

// ---------------- K_gemm: gates_x = x_hat @ w_ih^T  (bf16 MFMA, 128x128 tiles)
// XOR-swizzled LDS (swizzle applied at the GLOBAL source so global_load_lds's
// fixed lane->LDS mapping lands data pre-swizzled; reader XORs the chunk).
// XCD-aware block decode: id%8 = XCD (round-robin dispatch heuristic); each
// XCD owns a contiguous 24-m-tile strip, n fastest -> A-tile reuse stays in
// that XCD's L2, B streams from L3.
__global__ __launch_bounds__(256) void k_gemm(const unsigned short* __restrict__ A,
                                              const unsigned short* __restrict__ Bw,
                                              unsigned short* __restrict__ C) {
  __shared__ unsigned short Asm[128 * 64];
  __shared__ unsigned short Bsm[128 * 64];
  const int tid = threadIdx.x;
  const int wave = tid >> 6, lane = tid & 63;
  const int q = lane >> 4, l16 = lane & 15;
  const int id = blockIdx.x;
  const int xcd = id & 7, j = id >> 3;
  const long m0 = ((long)xcd * 24 + (j >> 4)) * 128;   // 192 m-tiles
  const long n0 = (long)(j & 15) * 128;                // 16 n-tiles
  const int wm = wave & 1, wn = wave >> 1;
  f32x4 acc[4][4];
  f32x4 zz = {0.f, 0.f, 0.f, 0.f};
#pragma unroll
  for (int i = 0; i < 4; ++i)
#pragma unroll
    for (int j2 = 0; j2 < 4; ++j2) acc[i][j2] = zz;
  const int srow = wave * 32 + (lane >> 3);
  const int csw = (lane & 7) ^ (srow & 7);             // swizzled source chunk
  const unsigned short* Ag = A + (m0 + srow) * 2048 + csw * 8;
  const unsigned short* Bg = Bw + (n0 + srow) * 2048 + csw * 8;
  for (int kt = 0; kt < 32; ++kt) {
    __syncthreads();
#pragma unroll
    for (int i = 0; i < 4; ++i) {
      g2lds16(Ag + (long)kt * 64 + (long)i * 8 * 2048, Asm + (wave * 32 + i * 8) * 64);
      g2lds16(Bg + (long)kt * 64 + (long)i * 8 * 2048, Bsm + (wave * 32 + i * 8) * 64);
    }
    asm volatile("s_waitcnt vmcnt(0)" ::: "memory");
    __syncthreads();
#pragma unroll
    for (int ks = 0; ks < 64; ks += 32) {
      const int ca = (ks >> 3) + q;                    // logical chunk 0..7
      const int px = (ca ^ (l16 & 7)) * 8;             // swizzled position
      s16x8 af[4], bv[4];
#pragma unroll
      for (int mt = 0; mt < 4; ++mt)
        af[mt] = *(const s16x8*)&Asm[(wm * 64 + mt * 16 + l16) * 64 + px];
#pragma unroll
      for (int nt = 0; nt < 4; ++nt)
        bv[nt] = *(const s16x8*)&Bsm[(wn * 64 + nt * 16 + l16) * 64 + px];
#pragma unroll
      for (int mt = 0; mt < 4; ++mt)
#pragma unroll
        for (int nt = 0; nt < 4; ++nt)
          acc[mt][nt] = __builtin_amdgcn_mfma_f32_16x16x32_bf16(af[mt], bv[nt], acc[mt][nt], 0, 0, 0);
    }
  }
#pragma unroll
  for (int mt = 0; mt < 4; ++mt)
#pragma unroll
    for (int nt = 0; nt < 4; ++nt)
#pragma unroll
      for (int r = 0; r < 4; ++r) {
        long m = m0 + wm * 64 + mt * 16 + q * 4 + r;
        long n = n0 + wn * 64 + nt * 16 + l16;
        C[m * 2048 + n] = f2bf(acc[mt][nt][r]);
      }
}

// ---------------- K_rec: persistent LSTM scan -----------------------------
// block (bt,g): bt = blockIdx&15, g = blockIdx>>4. Owns batch rows
// [bt*32,+32), h-cols [g*32,+32) (gate cols q*512+g*32+r).
// w_hh fragments PINNED in VGPRs (asm anti-remat). h(t-1) staged once per
// step into LDS via system-scope (sc0 sc1) loads; flags via system-scope
// relaxed stores after __syncthreads' vmcnt(0) drain. NO acquire/release ->
// no L2 writeback/invalidate; placement-independent via coherent L3.
__global__ __launch_bounds__(256, 1) void k_rec(const unsigned short* __restrict__ gx,
                                                const unsigned short* __restrict__ whh_b,
                                                const float* __restrict__ b_ih,
                                                const float* __restrict__ b_hh,
                                                unsigned short* __restrict__ h_buf,
                                                float* __restrict__ out,
                                                unsigned int* __restrict__ bar) {
  __shared__ unsigned short hs[32 * 528];   // h(t-1) stage, rows padded to 528
  __shared__ float gsm[4 * 32 * 36];        // [quad][colN 32][rowM pad36]
  const int tid = threadIdx.x;
  const int wave = tid >> 6, lane = tid & 63;   // wave == gate quadrant
  const int q = lane >> 4, l16 = lane & 15;
  const int bt = blockIdx.x & 15, g = blockIdx.x >> 4;
  const int b0 = bt * 32;
  const int pm = tid >> 3, pr = (tid & 7) * 4;  // pointwise: row pm, cols pr..pr+3
  const int srow = tid >> 3, st7 = tid & 7;     // stage: row srow, ull lane st7
  unsigned int* slots = &bar[bt * 16];

  // w_hh fragments -> registers (once), pinned against rematerialization
  s16x8 wreg[32];
#pragma unroll
  for (int nt = 0; nt < 2; ++nt) {
    const unsigned short* wp = whh_b + (long)(wave * 512 + g * 32 + nt * 16 + l16) * 512 + q * 8;
#pragma unroll
    for (int kk = 0; kk < 16; ++kk)
      wreg[nt * 16 + kk] = *(const s16x8*)(wp + kk * 32);
  }
#pragma unroll
  for (int i = 0; i < 32; ++i) asm volatile("" : "+v"(wreg[i]));

  float bias_[16];
#pragma unroll
  for (int qq = 0; qq < 4; ++qq)
#pragma unroll
    for (int rr = 0; rr < 4; ++rr) {
      int j = qq * 512 + g * 32 + pr + rr;
      bias_[qq * 4 + rr] = b_ih[j] + b_hh[j];
    }
  float creg[4] = {0.f, 0.f, 0.f, 0.f};
  const f32x4 zz = {0.f, 0.f, 0.f, 0.f};

  for (int t = 0; t < 48; ++t) {
    // prefetch gx (plain cached loads; read-only, L2 stays warm now)
    u16x4 gxr[4];
    const unsigned short* gp = gx + ((long)t * 512 + b0 + pm) * 2048 + g * 32 + pr;
#pragma unroll
    for (int qq = 0; qq < 4; ++qq) gxr[qq] = *(const u16x4*)(gp + qq * 512);

    f32x4 acc[2][2] = {{zz, zz}, {zz, zz}};
    if (t > 0) {
      // wait for the 16 producer slots of this bt group (relaxed sys polls)
      if (wave == 0 && lane < 16) {
        while (ld_sys_u32(&slots[lane]) < (unsigned)t)
          __builtin_amdgcn_s_sleep(1);
      }
      __syncthreads();
      // stage h(t-1)[b0:b0+32, 0:512] -> LDS (sys loads bypass stale L1/L2)
      const u64* hp = (const u64*)(h_buf + ((t - 1) & 1) * (512 * 512) + (long)b0 * 512);
      u64 tmp[16];
#pragma unroll
      for (int j = 0; j < 16; ++j)
        tmp[j] = ld_sys_u64(hp + (long)srow * 128 + st7 + 8 * j);
#pragma unroll
      for (int j = 0; j < 16; ++j)
        *(u64*)&hs[srow * 528 + (st7 + 8 * j) * 4] = tmp[j];
      __syncthreads();
#pragma unroll
      for (int kk = 0; kk < 16; ++kk) {
        s16x8 af0 = *(const s16x8*)&hs[l16 * 528 + kk * 32 + q * 8];
        s16x8 af1 = *(const s16x8*)&hs[(16 + l16) * 528 + kk * 32 + q * 8];
        acc[0][0] = __builtin_amdgcn_mfma_f32_16x16x32_bf16(af0, wreg[kk],      acc[0][0], 0, 0, 0);
        acc[0][1] = __builtin_amdgcn_mfma_f32_16x16x32_bf16(af0, wreg[16 + kk], acc[0][1], 0, 0, 0);
        acc[1][0] = __builtin_amdgcn_mfma_f32_16x16x32_bf16(af1, wreg[kk],      acc[1][0], 0, 0, 0);
        acc[1][1] = __builtin_amdgcn_mfma_f32_16x16x32_bf16(af1, wreg[16 + kk], acc[1][1], 0, 0, 0);
      }
    }
    // acc -> gsm[wave][colN][rowM]; rows mt*16+q*4..+3 contiguous => b128 store
#pragma unroll
    for (int mt = 0; mt < 2; ++mt)
#pragma unroll
      for (int nt = 0; nt < 2; ++nt)
        *(f32x4*)&gsm[(wave * 32 + nt * 16 + l16) * 36 + mt * 16 + q * 4] = acc[mt][nt];
    __syncthreads();
    // pointwise LSTM cell: thread owns (row b0+pm, cols g*32+pr..+3)
    float hval[4];
#pragma unroll
    for (int rr = 0; rr < 4; ++rr) {
      float gv[4];
#pragma unroll
      for (int qq = 0; qq < 4; ++qq)
        gv[qq] = gsm[(qq * 32 + pr + rr) * 36 + pm] + bf2f(gxr[qq][rr]) + bias_[qq * 4 + rr];
      float is = sigmoidf_(gv[0]);
      float fs = sigmoidf_(gv[1]);
      float gt = tanhf(gv[2]);
      float os = sigmoidf_(gv[3]);
      creg[rr] = fs * creg[rr] + is * gt;
      hval[rr] = os * tanhf(creg[rr]);
    }
    // publish h slice via system-scope stores (land in coherent L3)
    u16x4 hb = {f2bf(hval[0]), f2bf(hval[1]), f2bf(hval[2]), f2bf(hval[3])};
    u64 hb8;
    __builtin_memcpy(&hb8, &hb, 8);
    st_sys_u64((u64*)&h_buf[(t & 1) * (512 * 512) + (b0 + pm) * 512 + g * 32 + pr], hb8);
    f32x4 ov = {hval[0], hval[1], hval[2], hval[3]};
    __builtin_nontemporal_store(ov, (f32x4*)&out[(long)(b0 + pm) * (T_ * H_) + (long)t * H_ + g * 32 + pr]);
    __syncthreads();   // drains vmcnt(0): h stores at L3 before flag
    if (t < 47 && tid == 0)
      st_sys_u32(&slots[g], (unsigned)(t + 1));
  }
}

extern "C" void kernel_launch(void* const* d_in, const int* in_sizes, int n_in,
                              void* d_out, int out_size, void* d_ws, size_t ws_size,
                              hipStream_t stream) {
  const float* input  = (const float*)d_in[0];
  const float* attn_w = (const float*)d_in[1];
  const float* attn_b = (const float*)d_in[2];
  const float* w_ih   = (const float*)d_in[3];
  const float* w_hh   = (const float*)d_in[4];
  const float* b_ih   = (const float*)d_in[5];
  const float* b_hh   = (const float*)d_in[6];
  float* out = (float*)d_out;

  char* ws = (char*)d_ws;
  unsigned int* bar     = (unsigned int*)ws;                   // [0, 1024)
  float* a_ws           = (float*)(ws + 1024);                 // 512*128*4    = 262144
  unsigned short* h_buf = (unsigned short*)(ws + 263168);      // 2*512*512*2  = 1048576
  unsigned short* whh_b = (unsigned short*)(ws + 1311744);     // 2048*512*2   = 2097152
  unsigned short* wih_b = (unsigned short*)(ws + 3408896);     // 2048*2048*2  = 8388608
  unsigned short* x_hat = (unsigned short*)(ws + 11797504);    // 24576*2048*2 = 100663296
  unsigned short* gxws  = (unsigned short*)(ws + 112460800);   // 24576*2048*2 = 100663296

  (void)hipMemsetAsync(d_ws, 0, 1024, stream);
  hipLaunchKernelGGL(k_prep, dim3(5120), dim3(256), 0, stream, w_ih, w_hh, wih_b, whh_b);
  hipLaunchKernelGGL(k_ex, dim3(512), dim3(128), 0, stream, input, attn_w, attn_b, a_ws);
  hipLaunchKernelGGL(k_xhat, dim3(24576), dim3(256), 0, stream, input, a_ws, x_hat);
  hipLaunchKernelGGL(k_gemm, dim3(3072), dim3(256), 0, stream, x_hat, wih_b, gxws);
  hipLaunchKernelGGL(k_rec, dim3(256), dim3(256), 0, stream, gxws, whh_b, b_ih, b_hh, h_buf, out, bar);
}